// Round 1
// baseline (285.020 us; speedup 1.0000x reference)
//
#include <hip/hip_runtime.h>

typedef __bf16 bf16;
typedef __bf16 bf16x8 __attribute__((ext_vector_type(8)));
typedef float f32x4 __attribute__((ext_vector_type(4)));

static_assert(sizeof(bf16x8) == 16, "bf16x8 must be 16B");

#define MFMA16x16x32(a, b, c) __builtin_amdgcn_mfma_f32_16x16x32_bf16((a), (b), (c), 0, 0, 0)

// problem constants
#define NB 2
#define NL 1024
#define ND 1024
#define NH 16
#define NHD 64
#define NP 2047
#define NBH (NB * NH)  // 32

// ---------------- kernel 0: split Er f32 -> hi/lo bf16 ----------------
__global__ __launch_bounds__(256) void split_er_k(const float* __restrict__ er,
                                                  bf16* __restrict__ hi,
                                                  bf16* __restrict__ lo, int n) {
  int i = blockIdx.x * 256 + threadIdx.x;
  if (i < n) {
    float v = er[i];
    bf16 h = (bf16)v;
    hi[i] = h;
    lo[i] = (bf16)(v - (float)h);
  }
}

// ---------------- kernel 1: QKV projection GEMM ----------------
// X [2048][1024] f32, W [1024][3072] f32, bias [3072] f32.
// Q section (n<1024) computed with 3-term hi/lo MFMA for precision.
// outputs: qh/ql [BH][L][64], kk [BH][L][64], vt [BH][64][L]  (all bf16)
__global__ __launch_bounds__(256) void qkv_gemm_k(const float* __restrict__ X,
                                                  const float* __restrict__ W,
                                                  const float* __restrict__ bias,
                                                  bf16* __restrict__ qh, bf16* __restrict__ ql,
                                                  bf16* __restrict__ kk, bf16* __restrict__ vt) {
  __shared__ bf16 xh[64][40], xl[64][40], wh[64][40], wl[64][40];  // padded: +8 breaks bank conflicts
  const int t = threadIdx.x;
  const int lane = t & 63;
  const int wm = t >> 6;
  const int cl = lane & 15;
  const int g = lane >> 4;
  const int n0 = blockIdx.x * 64;
  const int m0 = blockIdx.y * 64;
  const bool isQ = (n0 < ND);

  f32x4 acc[4] = {};

  const int xrow = t >> 2, xkc = (t & 3) * 8;
  const int wkr = t >> 3, wnc = (t & 7) * 8;

  for (int k0 = 0; k0 < ND; k0 += 32) {
    // stage X tile [64][32] as hi (+lo for Q blocks)
    {
      const float* xp = X + (size_t)(m0 + xrow) * ND + k0 + xkc;
      float4 v0 = *(const float4*)xp;
      float4 v1 = *(const float4*)(xp + 4);
      float v[8] = {v0.x, v0.y, v0.z, v0.w, v1.x, v1.y, v1.z, v1.w};
      bf16x8 h8, l8;
#pragma unroll
      for (int e = 0; e < 8; ++e) {
        bf16 hh = (bf16)v[e];
        h8[e] = hh;
        l8[e] = (bf16)(v[e] - (float)hh);
      }
      *(bf16x8*)&xh[xrow][xkc] = h8;
      if (isQ) *(bf16x8*)&xl[xrow][xkc] = l8;
    }
    // stage W tile [32][64] transposed into wh/wl [n][k]
    {
      const float* wp = W + (size_t)(k0 + wkr) * (3 * ND) + n0 + wnc;
      float4 v0 = *(const float4*)wp;
      float4 v1 = *(const float4*)(wp + 4);
      float v[8] = {v0.x, v0.y, v0.z, v0.w, v1.x, v1.y, v1.z, v1.w};
#pragma unroll
      for (int e = 0; e < 8; ++e) {
        bf16 hh = (bf16)v[e];
        wh[wnc + e][wkr] = hh;
        if (isQ) wl[wnc + e][wkr] = (bf16)(v[e] - (float)hh);
      }
    }
    __syncthreads();
    bf16x8 ah = *(const bf16x8*)&xh[wm * 16 + cl][g * 8];
    bf16x8 al = {};
    if (isQ) al = *(const bf16x8*)&xl[wm * 16 + cl][g * 8];
#pragma unroll
    for (int nf = 0; nf < 4; ++nf) {
      bf16x8 bh8 = *(const bf16x8*)&wh[nf * 16 + cl][g * 8];
      acc[nf] = MFMA16x16x32(ah, bh8, acc[nf]);
      if (isQ) {
        bf16x8 bl8 = *(const bf16x8*)&wl[nf * 16 + cl][g * 8];
        acc[nf] = MFMA16x16x32(ah, bl8, acc[nf]);
        acc[nf] = MFMA16x16x32(al, bh8, acc[nf]);
      }
    }
    __syncthreads();
  }

  // epilogue: bias + scatter into attention layouts
#pragma unroll
  for (int nf = 0; nf < 4; ++nf) {
#pragma unroll
    for (int reg = 0; reg < 4; ++reg) {
      const int gm = m0 + wm * 16 + g * 4 + reg;   // token row
      const int gn = n0 + nf * 16 + cl;            // qkv col
      float val = acc[nf][reg] + bias[gn];
      const int bb = gm >> 10, lpos = gm & 1023;
      const int sec = gn >> 10, hc = gn & 1023;
      const int hh = hc >> 6, dd = hc & 63;
      const int bh = bb * NH + hh;
      if (sec == 0) {
        bf16 hi = (bf16)val;
        qh[(size_t)(bh * NL + lpos) * NHD + dd] = hi;
        ql[(size_t)(bh * NL + lpos) * NHD + dd] = (bf16)(val - (float)hi);
      } else if (sec == 1) {
        kk[(size_t)(bh * NL + lpos) * NHD + dd] = (bf16)val;
      } else {
        vt[(size_t)(bh * NHD + dd) * NL + lpos] = (bf16)val;  // V transposed for PV B-frags
      }
    }
  }
}

// ---------------- kernel 2: causal attention with relative bias ----------------
// 1 wave per block; block = (bh, 16-row q tile). Flash-style over 32-wide j chunks.
__global__ __launch_bounds__(64) void attn_k(const bf16* __restrict__ qh, const bf16* __restrict__ ql,
                                             const bf16* __restrict__ kk, const bf16* __restrict__ vt,
                                             const bf16* __restrict__ erh, const bf16* __restrict__ erl,
                                             bf16* __restrict__ ao) {
  __shared__ float s_lds[16][33];
  __shared__ float e_lds[16][49];
  __shared__ float f_lds[16];

  const int l = threadIdx.x;
  const int cl = l & 15;
  const int g = l >> 4;
  const int blk = blockIdx.x;
  const int itile = blk & (NL / 16 - 1);
  const int bh = blk >> 6;
  const int h = bh & (NH - 1);
  const int i0 = itile * 16;

  // Q fragments (A-operand: row = lane&15, k = (lane>>4)*8 + e)
  const bf16* qhb = qh + (size_t)(bh * NL + i0 + cl) * NHD + g * 8;
  const bf16* qlb = ql + (size_t)(bh * NL + i0 + cl) * NHD + g * 8;
  const bf16x8 q_h0 = *(const bf16x8*)qhb;
  const bf16x8 q_h1 = *(const bf16x8*)(qhb + 32);
  const bf16x8 q_l0 = *(const bf16x8*)qlb;
  const bf16x8 q_l1 = *(const bf16x8*)(qlb + 32);

  f32x4 acc_o[4] = {};
  float m_s = -1e30f, l_s = 0.0f;

  const int nchunks = i0 / 32 + 1;
  for (int jc = 0; jc < nchunks; ++jc) {
    const int j0 = jc * 32;
    const int delta = i0 - j0;  // >= 0

    // ---- S = Q K^T (q_hi only; error negligible after /8 scale) ----
    f32x4 acc_s[2];
#pragma unroll
    for (int jn = 0; jn < 2; ++jn) {
      const bf16* kb = kk + (size_t)(bh * NL + j0 + jn * 16 + cl) * NHD + g * 8;
      bf16x8 kf0 = *(const bf16x8*)kb;
      bf16x8 kf1 = *(const bf16x8*)(kb + 32);
      f32x4 a = {};
      a = MFMA16x16x32(q_h0, kf0, a);
      a = MFMA16x16x32(q_h1, kf1, a);
      acc_s[jn] = a;
    }
    // ---- bias tiles: QE window over o = i-j in [delta-32, delta+15], 3-term split ----
    f32x4 acc_e[3];
#pragma unroll
    for (int tt = 0; tt < 3; ++tt) {
      const int o = delta - 32 + tt * 16 + cl;
      const int p = (o <= 0) ? -o : (NP - o);  // (j-i) mod P
      const bf16* ebh = erh + (size_t)(h * NP + p) * NHD + g * 8;
      const bf16* ebl = erl + (size_t)(h * NP + p) * NHD + g * 8;
      bf16x8 eh0 = *(const bf16x8*)ebh;
      bf16x8 eh1 = *(const bf16x8*)(ebh + 32);
      bf16x8 el0 = *(const bf16x8*)ebl;
      bf16x8 el1 = *(const bf16x8*)(ebl + 32);
      f32x4 a = {};
      a = MFMA16x16x32(q_h0, eh0, a);
      a = MFMA16x16x32(q_h1, eh1, a);
      a = MFMA16x16x32(q_h0, el0, a);
      a = MFMA16x16x32(q_h1, el1, a);
      a = MFMA16x16x32(q_l0, eh0, a);
      a = MFMA16x16x32(q_l1, eh1, a);
      acc_e[tt] = a;
    }
    // ---- spill S (scaled) and E tiles to LDS (C-layout: row=g*4+reg, col=cl) ----
#pragma unroll
    for (int reg = 0; reg < 4; ++reg) {
      const int row = g * 4 + reg;
      s_lds[row][cl] = acc_s[0][reg] * 0.125f;
      s_lds[row][16 + cl] = acc_s[1][reg] * 0.125f;
      e_lds[row][cl] = acc_e[0][reg];
      e_lds[row][16 + cl] = acc_e[1][reg];
      e_lds[row][32 + cl] = acc_e[2][reg];
    }
    __syncthreads();

    // ---- online softmax; lane handles row=cl, cols g*8..g*8+7 ----
    float sv[8];
    float tmax = -1e30f;
#pragma unroll
    for (int cc = 0; cc < 8; ++cc) {
      const int c = g * 8 + cc;
      float v = s_lds[cl][c] + e_lds[cl][cl - c + 32];  // idx in [1,47]
      if (j0 + c > i0 + cl) v = -1e30f;                 // causal mask
      sv[cc] = v;
      tmax = fmaxf(tmax, v);
    }
    tmax = fmaxf(tmax, __shfl_xor(tmax, 16));
    tmax = fmaxf(tmax, __shfl_xor(tmax, 32));
    const float m_new = fmaxf(m_s, tmax);
    const float fsc = __expf(m_s - m_new);
    float psum = 0.0f;
    bf16x8 pf;  // P values land exactly in A-frag layout — no LDS round trip
#pragma unroll
    for (int cc = 0; cc < 8; ++cc) {
      float pv = __expf(sv[cc] - m_new);
      psum += pv;
      pf[cc] = (bf16)pv;
    }
    psum += __shfl_xor(psum, 16);
    psum += __shfl_xor(psum, 32);
    l_s = l_s * fsc + psum;
    m_s = m_new;
    if (l < 16) f_lds[l] = fsc;  // row r = l for lanes 0..15
    __syncthreads();

    float fr[4];
#pragma unroll
    for (int reg = 0; reg < 4; ++reg) fr[reg] = f_lds[g * 4 + reg];
#pragma unroll
    for (int t4 = 0; t4 < 4; ++t4) {
#pragma unroll
      for (int reg = 0; reg < 4; ++reg) acc_o[t4][reg] *= fr[reg];
    }
    // ---- O += P V  (B-frag from transposed V: col=d, k=j contiguous) ----
#pragma unroll
    for (int t4 = 0; t4 < 4; ++t4) {
      const bf16* vb = vt + (size_t)(bh * NHD + t4 * 16 + cl) * NL + j0 + g * 8;
      bf16x8 vf = *(const bf16x8*)vb;
      acc_o[t4] = MFMA16x16x32(pf, vf, acc_o[t4]);
    }
    __syncthreads();
  }

  if (l < 16) f_lds[l] = 1.0f / l_s;
  __syncthreads();
  const int bb = bh >> 4;  // NH == 16
#pragma unroll
  for (int t4 = 0; t4 < 4; ++t4) {
#pragma unroll
    for (int reg = 0; reg < 4; ++reg) {
      const int irow = i0 + g * 4 + reg;
      const int col = h * NHD + t4 * 16 + cl;
      float on = acc_o[t4][reg] * f_lds[g * 4 + reg];
      ao[(size_t)(bb * NL + irow) * ND + col] = (bf16)on;
    }
  }
}

// ---------------- kernel 3: output projection ----------------
// A = attn out bf16 [2048][1024], W_o [1024][1024] f32, out f32.
__global__ __launch_bounds__(256) void out_gemm_k(const bf16* __restrict__ A,
                                                  const float* __restrict__ W,
                                                  const float* __restrict__ bias,
                                                  float* __restrict__ out) {
  __shared__ bf16 alds[64][40], wh[64][40];
  const int t = threadIdx.x;
  const int lane = t & 63, wm = t >> 6;
  const int cl = lane & 15, g = lane >> 4;
  const int n0 = blockIdx.x * 64, m0 = blockIdx.y * 64;
  f32x4 acc[4] = {};
  const int arow = t >> 2, akc = (t & 3) * 8;
  const int wkr = t >> 3, wnc = (t & 7) * 8;
  for (int k0 = 0; k0 < ND; k0 += 32) {
    *(bf16x8*)&alds[arow][akc] = *(const bf16x8*)(A + (size_t)(m0 + arow) * ND + k0 + akc);
    {
      const float* wp = W + (size_t)(k0 + wkr) * ND + n0 + wnc;
      float4 v0 = *(const float4*)wp;
      float4 v1 = *(const float4*)(wp + 4);
      float v[8] = {v0.x, v0.y, v0.z, v0.w, v1.x, v1.y, v1.z, v1.w};
#pragma unroll
      for (int e = 0; e < 8; ++e) wh[wnc + e][wkr] = (bf16)v[e];
    }
    __syncthreads();
    bf16x8 a8 = *(const bf16x8*)&alds[wm * 16 + cl][g * 8];
#pragma unroll
    for (int nf = 0; nf < 4; ++nf) {
      bf16x8 b8 = *(const bf16x8*)&wh[nf * 16 + cl][g * 8];
      acc[nf] = MFMA16x16x32(a8, b8, acc[nf]);
    }
    __syncthreads();
  }
#pragma unroll
  for (int nf = 0; nf < 4; ++nf) {
#pragma unroll
    for (int reg = 0; reg < 4; ++reg) {
      const int gm = m0 + wm * 16 + g * 4 + reg;
      const int gn = n0 + nf * 16 + cl;
      out[(size_t)gm * ND + gn] = acc[nf][reg] + bias[gn];
    }
  }
}

extern "C" void kernel_launch(void* const* d_in, const int* in_sizes, int n_in,
                              void* d_out, int out_size, void* d_ws, size_t ws_size,
                              hipStream_t stream) {
  (void)in_sizes; (void)n_in; (void)out_size; (void)ws_size;
  const float* x = (const float*)d_in[0];
  // d_in[1] = causal mask — structural (triu k=1), computed inline
  const float* Wqkv = (const float*)d_in[2];
  const float* bqkv = (const float*)d_in[3];
  const float* Wo = (const float*)d_in[4];
  const float* bo = (const float*)d_in[5];
  const float* Er = (const float*)d_in[6];

  char* ws = (char*)d_ws;
  size_t off = 0;
  auto take = [&](size_t bytes) {
    char* p = ws + off;
    off += (bytes + 255) & ~(size_t)255;
    return p;
  };
  const size_t erN = (size_t)NH * NP * NHD;       // 2,096,128
  const size_t qkN = (size_t)NBH * NL * NHD;      // 2,097,152
  bf16* erh = (bf16*)take(erN * 2);
  bf16* erl = (bf16*)take(erN * 2);
  bf16* qhw = (bf16*)take(qkN * 2);
  bf16* qlw = (bf16*)take(qkN * 2);
  bf16* kw  = (bf16*)take(qkN * 2);
  bf16* vtw = (bf16*)take(qkN * 2);
  bf16* aow = (bf16*)take((size_t)NB * NL * ND * 2);
  // total ~29.4 MB of workspace

  split_er_k<<<(int)((erN + 255) / 256), 256, 0, stream>>>(Er, erh, erl, (int)erN);
  qkv_gemm_k<<<dim3(48, 32), 256, 0, stream>>>(x, Wqkv, bqkv, qhw, qlw, kw, vtw);
  attn_k<<<NBH * (NL / 16), 64, 0, stream>>>(qhw, qlw, kw, vtw, erh, erl, aow);
  out_gemm_k<<<dim3(16, 32), 256, 0, stream>>>(aow, Wo, bo, (float*)d_out);
}

// Round 2
// 210.785 us; speedup vs baseline: 1.3522x; 1.3522x over previous
//
#include <hip/hip_runtime.h>

typedef __bf16 bf16;
typedef __bf16 bf16x8 __attribute__((ext_vector_type(8)));
typedef float f32x4 __attribute__((ext_vector_type(4)));

static_assert(sizeof(bf16x8) == 16, "bf16x8 must be 16B");

#define MFMA16x16x32(a, b, c) __builtin_amdgcn_mfma_f32_16x16x32_bf16((a), (b), (c), 0, 0, 0)

// problem constants
#define NB 2
#define NL 1024
#define ND 1024
#define NH 16
#define NHD 64
#define NP 2047
#define NBH (NB * NH)  // 32

// wave-synchronous LDS fence: single-wave blocks need no s_barrier (no vmcnt drain!)
__device__ __forceinline__ void wave_sync_lds() {
  __builtin_amdgcn_sched_barrier(0);
  asm volatile("s_waitcnt lgkmcnt(0)" ::: "memory");
  __builtin_amdgcn_sched_barrier(0);
}

// ---------------- kernel 0: split Er f32 -> hi/lo bf16 ----------------
__global__ __launch_bounds__(256) void split_er_k(const float* __restrict__ er,
                                                  bf16* __restrict__ hi,
                                                  bf16* __restrict__ lo, int n) {
  int i = blockIdx.x * 256 + threadIdx.x;
  if (i < n) {
    float v = er[i];
    bf16 h = (bf16)v;
    hi[i] = h;
    lo[i] = (bf16)(v - (float)h);
  }
}

// ---------------- kernel 0b: transpose + split W [K][N] f32 -> WT [N][K] bf16 ----------------
// WT_l written only for n < n_lo (Q precision section).
__global__ __launch_bounds__(256) void trans_split_k(const float* __restrict__ W, int N, int K,
                                                     int n_lo, bf16* __restrict__ WT_h,
                                                     bf16* __restrict__ WT_l) {
  __shared__ float tile[64][68];
  const int n0 = blockIdx.x * 64, k0 = blockIdx.y * 64;
  const int t = threadIdx.x;
  const int rc = t & 15;   // n col group (4 floats)
  const int rr0 = t >> 4;  // k row base
#pragma unroll
  for (int i = 0; i < 4; ++i) {
    const int row = rr0 + i * 16;
    float4 v = *(const float4*)(W + (size_t)(k0 + row) * N + n0 + rc * 4);
    *(float4*)&tile[row][rc * 4] = v;
  }
  __syncthreads();
  const int n = t >> 2, kc = (t & 3) * 16;
  bf16x8 h0, h1, l0, l1;
#pragma unroll
  for (int e = 0; e < 8; ++e) {
    float v = tile[kc + e][n];
    bf16 hh = (bf16)v;
    h0[e] = hh;
    l0[e] = (bf16)(v - (float)hh);
  }
#pragma unroll
  for (int e = 0; e < 8; ++e) {
    float v = tile[kc + 8 + e][n];
    bf16 hh = (bf16)v;
    h1[e] = hh;
    l1[e] = (bf16)(v - (float)hh);
  }
  bf16* dst = WT_h + (size_t)(n0 + n) * K + k0 + kc;
  *(bf16x8*)dst = h0;
  *(bf16x8*)(dst + 8) = h1;
  if (WT_l != nullptr && (n0 + n) < n_lo) {
    bf16* dstl = WT_l + (size_t)(n0 + n) * K + k0 + kc;
    *(bf16x8*)dstl = l0;
    *(bf16x8*)(dstl + 8) = l1;
  }
}

// ---------------- kernel 1: QKV projection GEMM ----------------
// X [2048][1024] f32 (split to hi/lo at stage time), WT hi/lo [3072][1024] bf16 pre-transposed.
// Q section (n<1024): 3-term hi/lo MFMA. outputs qh/ql [BH][L][64], kk [BH][L][64], vt [BH][64][L].
__global__ __launch_bounds__(256) void qkv_gemm_k(const float* __restrict__ X,
                                                  const bf16* __restrict__ WTh,
                                                  const bf16* __restrict__ WTl,
                                                  const float* __restrict__ bias,
                                                  bf16* __restrict__ qh, bf16* __restrict__ ql,
                                                  bf16* __restrict__ kk, bf16* __restrict__ vt) {
  __shared__ bf16 xh[64][40], xl[64][40], wh[64][40], wl[64][40];
  const int t = threadIdx.x;
  const int lane = t & 63;
  const int wm = t >> 6;
  const int cl = lane & 15;
  const int g = lane >> 4;
  const int n0 = blockIdx.x * 64;
  const int m0 = blockIdx.y * 64;
  const bool isQ = (n0 < ND);

  f32x4 acc[4] = {};
  const int xrow = t >> 2, xkc = (t & 3) * 8;

  for (int k0 = 0; k0 < ND; k0 += 32) {
    // stage X tile [64][32] (f32 -> hi/lo bf16)
    {
      const float* xp = X + (size_t)(m0 + xrow) * ND + k0 + xkc;
      float4 v0 = *(const float4*)xp;
      float4 v1 = *(const float4*)(xp + 4);
      float v[8] = {v0.x, v0.y, v0.z, v0.w, v1.x, v1.y, v1.z, v1.w};
      bf16x8 h8, l8;
#pragma unroll
      for (int e = 0; e < 8; ++e) {
        bf16 hh = (bf16)v[e];
        h8[e] = hh;
        l8[e] = (bf16)(v[e] - (float)hh);
      }
      *(bf16x8*)&xh[xrow][xkc] = h8;
      if (isQ) *(bf16x8*)&xl[xrow][xkc] = l8;
    }
    // stage W tile [64 n][32 k] straight from pre-transposed bf16
    {
      *(bf16x8*)&wh[xrow][xkc] = *(const bf16x8*)(WTh + (size_t)(n0 + xrow) * ND + k0 + xkc);
      if (isQ) *(bf16x8*)&wl[xrow][xkc] = *(const bf16x8*)(WTl + (size_t)(n0 + xrow) * ND + k0 + xkc);
    }
    __syncthreads();
    bf16x8 ah = *(const bf16x8*)&xh[wm * 16 + cl][g * 8];
    bf16x8 al = {};
    if (isQ) al = *(const bf16x8*)&xl[wm * 16 + cl][g * 8];
#pragma unroll
    for (int nf = 0; nf < 4; ++nf) {
      bf16x8 bh8 = *(const bf16x8*)&wh[nf * 16 + cl][g * 8];
      acc[nf] = MFMA16x16x32(ah, bh8, acc[nf]);
      if (isQ) {
        bf16x8 bl8 = *(const bf16x8*)&wl[nf * 16 + cl][g * 8];
        acc[nf] = MFMA16x16x32(ah, bl8, acc[nf]);
        acc[nf] = MFMA16x16x32(al, bh8, acc[nf]);
      }
    }
    __syncthreads();
  }

  // epilogue: bias + scatter into attention layouts
#pragma unroll
  for (int nf = 0; nf < 4; ++nf) {
#pragma unroll
    for (int reg = 0; reg < 4; ++reg) {
      const int gm = m0 + wm * 16 + g * 4 + reg;   // token row
      const int gn = n0 + nf * 16 + cl;            // qkv col
      float val = acc[nf][reg] + bias[gn];
      const int bb = gm >> 10, lpos = gm & 1023;
      const int sec = gn >> 10, hc = gn & 1023;
      const int hh = hc >> 6, dd = hc & 63;
      const int bh = bb * NH + hh;
      if (sec == 0) {
        bf16 hi = (bf16)val;
        qh[(size_t)(bh * NL + lpos) * NHD + dd] = hi;
        ql[(size_t)(bh * NL + lpos) * NHD + dd] = (bf16)(val - (float)hi);
      } else if (sec == 1) {
        kk[(size_t)(bh * NL + lpos) * NHD + dd] = (bf16)val;
      } else {
        vt[(size_t)(bh * NHD + dd) * NL + lpos] = (bf16)val;  // V transposed for PV B-frags
      }
    }
  }
}

// ---------------- kernel 2: causal attention with relative bias ----------------
// 1 wave per block, NO barriers (wave-synchronous LDS). 64-wide j chunks.
__global__ __launch_bounds__(64) void attn_k(const bf16* __restrict__ qh, const bf16* __restrict__ ql,
                                             const bf16* __restrict__ kk, const bf16* __restrict__ vt,
                                             const bf16* __restrict__ erh, const bf16* __restrict__ erl,
                                             bf16* __restrict__ ao) {
  __shared__ float s_lds[16][68];
  __shared__ float e_lds[16][84];
  __shared__ bf16 p_lds[16][72];

  const int l = threadIdx.x;
  const int cl = l & 15;
  const int g = l >> 4;
  const int blk = blockIdx.x;
  const int itile = blk & 63;
  const int bh = blk >> 6;
  const int h = bh & (NH - 1);
  const int i0 = itile * 16;

  // Q fragments (A-operand: row = lane&15, k = (lane>>4)*8 + e)
  const bf16* qhb = qh + (size_t)(bh * NL + i0 + cl) * NHD + g * 8;
  const bf16* qlb = ql + (size_t)(bh * NL + i0 + cl) * NHD + g * 8;
  const bf16x8 q_h0 = *(const bf16x8*)qhb;
  const bf16x8 q_h1 = *(const bf16x8*)(qhb + 32);
  const bf16x8 q_l0 = *(const bf16x8*)qlb;
  const bf16x8 q_l1 = *(const bf16x8*)(qlb + 32);

  f32x4 acc_o[4] = {};
  float m_s = -1e30f, l_s = 0.0f;

  const int nchunks = i0 / 64 + 1;
  for (int jc = 0; jc < nchunks; ++jc) {
    const int j0 = jc * 64;
    const int delta = i0 - j0;  // >= 0, multiple of 16

    // ---- V fragments first: independent of everything, max latency hiding ----
    bf16x8 vf[4][2];
#pragma unroll
    for (int t4 = 0; t4 < 4; ++t4) {
      const bf16* vb = vt + (size_t)(bh * NHD + t4 * 16 + cl) * NL + j0 + g * 8;
      vf[t4][0] = *(const bf16x8*)vb;
      vf[t4][1] = *(const bf16x8*)(vb + 32);
    }

    // ---- S = Q K^T (hi only) ----
    f32x4 acc_s[4];
#pragma unroll
    for (int jn = 0; jn < 4; ++jn) {
      const bf16* kb = kk + (size_t)(bh * NL + j0 + jn * 16 + cl) * NHD + g * 8;
      bf16x8 kf0 = *(const bf16x8*)kb;
      bf16x8 kf1 = *(const bf16x8*)(kb + 32);
      f32x4 a = {};
      a = MFMA16x16x32(q_h0, kf0, a);
      a = MFMA16x16x32(q_h1, kf1, a);
      acc_s[jn] = a;
    }

    // ---- bias: 5 Er tiles covering o = i-j in [delta-64, delta+15], 3-term split ----
    f32x4 acc_e[5];
#pragma unroll
    for (int tt = 0; tt < 5; ++tt) {
      const int o = delta - 64 + tt * 16 + cl;
      const int p = (o <= 0) ? -o : (NP - o);  // (j-i) mod P
      const bf16* ebh = erh + (size_t)(h * NP + p) * NHD + g * 8;
      const bf16* ebl = erl + (size_t)(h * NP + p) * NHD + g * 8;
      bf16x8 eh0 = *(const bf16x8*)ebh;
      bf16x8 eh1 = *(const bf16x8*)(ebh + 32);
      bf16x8 el0 = *(const bf16x8*)ebl;
      bf16x8 el1 = *(const bf16x8*)(ebl + 32);
      f32x4 c1 = {}, c2 = {};  // two independent chains (half the dep latency)
      c1 = MFMA16x16x32(q_h0, eh0, c1);
      c1 = MFMA16x16x32(q_h1, eh1, c1);
      c2 = MFMA16x16x32(q_h0, el0, c2);
      c2 = MFMA16x16x32(q_h1, el1, c2);
      c2 = MFMA16x16x32(q_l0, eh0, c2);
      c2 = MFMA16x16x32(q_l1, eh1, c2);
      acc_e[tt] = c1 + c2;
    }

    // ---- spill S and E to LDS (C-layout: row=g*4+reg, col=cl per 16-tile) ----
#pragma unroll
    for (int reg = 0; reg < 4; ++reg) {
      const int row = g * 4 + reg;
#pragma unroll
      for (int jn = 0; jn < 4; ++jn) s_lds[row][jn * 16 + cl] = acc_s[jn][reg];
#pragma unroll
      for (int tt = 0; tt < 5; ++tt) e_lds[row][tt * 16 + cl] = acc_e[tt][reg];
    }
    wave_sync_lds();

    // ---- online softmax; lane handles row=cl, cols g*16..g*16+15 ----
    float sv[16];
    float tmax = -3e38f;
#pragma unroll
    for (int cc = 0; cc < 16; ++cc) {
      const int c = g * 16 + cc;
      float v = fmaf(s_lds[cl][c], 0.125f, e_lds[cl][cl - c + 64]);  // idx in [1,79]
      if (c > delta + cl) v = -3e38f;  // causal mask: j0+c > i0+cl
      sv[cc] = v;
      tmax = fmaxf(tmax, v);
    }
    tmax = fmaxf(tmax, __shfl_xor(tmax, 16));
    tmax = fmaxf(tmax, __shfl_xor(tmax, 32));
    const float m_new = fmaxf(m_s, tmax);
    const float fsc = __builtin_amdgcn_exp2f((m_s - m_new) * 1.44269504f);
    float psum = 0.0f;
    bf16x8 plo, phi;
#pragma unroll
    for (int cc = 0; cc < 16; ++cc) {
      float pv = __builtin_amdgcn_exp2f((sv[cc] - m_new) * 1.44269504f);
      psum += pv;
      if (cc < 8) plo[cc & 7] = (bf16)pv;
      else        phi[cc & 7] = (bf16)pv;
    }
    psum += __shfl_xor(psum, 16);
    psum += __shfl_xor(psum, 32);
    l_s = l_s * fsc + psum;
    m_s = m_new;

    // P -> LDS (row=cl, cols g*16..+15), then read back in A-frag layout
    *(bf16x8*)&p_lds[cl][g * 16] = plo;
    *(bf16x8*)&p_lds[cl][g * 16 + 8] = phi;
    wave_sync_lds();
    bf16x8 pf0 = *(const bf16x8*)&p_lds[cl][g * 8];
    bf16x8 pf1 = *(const bf16x8*)&p_lds[cl][32 + g * 8];

    // rescale O by exp(m_old - m_new) per row, factors via shfl (no LDS trip)
    float fr[4];
#pragma unroll
    for (int reg = 0; reg < 4; ++reg) fr[reg] = __shfl(fsc, g * 4 + reg);
#pragma unroll
    for (int t4 = 0; t4 < 4; ++t4) {
#pragma unroll
      for (int reg = 0; reg < 4; ++reg) acc_o[t4][reg] *= fr[reg];
    }
    // ---- O += P V ----
#pragma unroll
    for (int t4 = 0; t4 < 4; ++t4) {
      acc_o[t4] = MFMA16x16x32(pf0, vf[t4][0], acc_o[t4]);
      acc_o[t4] = MFMA16x16x32(pf1, vf[t4][1], acc_o[t4]);
    }
  }

  const float inv = 1.0f / l_s;  // uniform per cl
  float fr[4];
#pragma unroll
  for (int reg = 0; reg < 4; ++reg) fr[reg] = __shfl(inv, g * 4 + reg);
  const int bb = bh >> 4;  // NH == 16
#pragma unroll
  for (int t4 = 0; t4 < 4; ++t4) {
#pragma unroll
    for (int reg = 0; reg < 4; ++reg) {
      const int irow = i0 + g * 4 + reg;
      const int col = h * NHD + t4 * 16 + cl;
      ao[(size_t)(bb * NL + irow) * ND + col] = (bf16)(acc_o[t4][reg] * fr[reg]);
    }
  }
}

// ---------------- kernel 3: output projection ----------------
// A = attn out bf16 [2048][1024], WoT [1024][1024] bf16 pre-transposed, out f32.
__global__ __launch_bounds__(256) void out_gemm_k(const bf16* __restrict__ A,
                                                  const bf16* __restrict__ WT,
                                                  const float* __restrict__ bias,
                                                  float* __restrict__ out) {
  __shared__ bf16 alds[64][40], wh[64][40];
  const int t = threadIdx.x;
  const int lane = t & 63, wm = t >> 6;
  const int cl = lane & 15, g = lane >> 4;
  const int n0 = blockIdx.x * 64, m0 = blockIdx.y * 64;
  f32x4 acc[4] = {};
  const int arow = t >> 2, akc = (t & 3) * 8;
  for (int k0 = 0; k0 < ND; k0 += 32) {
    *(bf16x8*)&alds[arow][akc] = *(const bf16x8*)(A + (size_t)(m0 + arow) * ND + k0 + akc);
    *(bf16x8*)&wh[arow][akc] = *(const bf16x8*)(WT + (size_t)(n0 + arow) * ND + k0 + akc);
    __syncthreads();
    bf16x8 a8 = *(const bf16x8*)&alds[wm * 16 + cl][g * 8];
#pragma unroll
    for (int nf = 0; nf < 4; ++nf) {
      bf16x8 b8 = *(const bf16x8*)&wh[nf * 16 + cl][g * 8];
      acc[nf] = MFMA16x16x32(a8, b8, acc[nf]);
    }
    __syncthreads();
  }
#pragma unroll
  for (int nf = 0; nf < 4; ++nf) {
#pragma unroll
    for (int reg = 0; reg < 4; ++reg) {
      const int gm = m0 + wm * 16 + g * 4 + reg;
      const int gn = n0 + nf * 16 + cl;
      out[(size_t)gm * ND + gn] = acc[nf][reg] + bias[gn];
    }
  }
}

extern "C" void kernel_launch(void* const* d_in, const int* in_sizes, int n_in,
                              void* d_out, int out_size, void* d_ws, size_t ws_size,
                              hipStream_t stream) {
  (void)in_sizes; (void)n_in; (void)out_size; (void)ws_size;
  const float* x = (const float*)d_in[0];
  // d_in[1] = causal mask — structural (triu k=1), computed inline
  const float* Wqkv = (const float*)d_in[2];
  const float* bqkv = (const float*)d_in[3];
  const float* Wo = (const float*)d_in[4];
  const float* bo = (const float*)d_in[5];
  const float* Er = (const float*)d_in[6];

  char* ws = (char*)d_ws;
  size_t off = 0;
  auto take = [&](size_t bytes) {
    char* p = ws + off;
    off += (bytes + 255) & ~(size_t)255;
    return p;
  };
  const size_t erN = (size_t)NH * NP * NHD;   // 2,096,128
  const size_t qkN = (size_t)NBH * NL * NHD;  // 2,097,152
  bf16* erh = (bf16*)take(erN * 2);
  bf16* erl = (bf16*)take(erN * 2);
  bf16* qhw = (bf16*)take(qkN * 2);
  bf16* qlw = (bf16*)take(qkN * 2);
  bf16* kw  = (bf16*)take(qkN * 2);
  bf16* vtw = (bf16*)take(qkN * 2);
  bf16* wqkvth = (bf16*)take((size_t)3 * ND * ND * 2);  // [3072][1024]
  bf16* wqkvtl = (bf16*)take((size_t)ND * ND * 2);      // [1024][1024] (Q section only)
  bf16* woth   = (bf16*)take((size_t)ND * ND * 2);      // [1024][1024]
  bf16* aow = wqkvth;  // alias: wqkvth dead after qkv_gemm, aow born in attn
  // total ~35.7 MB of workspace

  split_er_k<<<(int)((erN + 255) / 256), 256, 0, stream>>>(Er, erh, erl, (int)erN);
  trans_split_k<<<dim3(48, 16), 256, 0, stream>>>(Wqkv, 3 * ND, ND, ND, wqkvth, wqkvtl);
  trans_split_k<<<dim3(16, 16), 256, 0, stream>>>(Wo, ND, ND, 0, woth, nullptr);
  qkv_gemm_k<<<dim3(48, 32), 256, 0, stream>>>(x, wqkvth, wqkvtl, bqkv, qhw, qlw, kw, vtw);
  attn_k<<<NBH * (NL / 16), 64, 0, stream>>>(qhw, qlw, kw, vtw, erh, erl, aow);
  out_gemm_k<<<dim3(16, 32), 256, 0, stream>>>(aow, woth, bo, (float*)d_out);
}

// Round 4
// 166.225 us; speedup vs baseline: 1.7147x; 1.2681x over previous
//
#include <hip/hip_runtime.h>

typedef __bf16 bf16;
typedef __bf16 bf16x8 __attribute__((ext_vector_type(8)));
typedef float f32x4 __attribute__((ext_vector_type(4)));

static_assert(sizeof(bf16x8) == 16, "bf16x8 must be 16B");

#define MFMA16x16x32(a, b, c) __builtin_amdgcn_mfma_f32_16x16x32_bf16((a), (b), (c), 0, 0, 0)

// problem constants
#define NB 2
#define NL 1024
#define ND 1024
#define NH 16
#define NHD 64
#define NP 2047
#define NBH (NB * NH)  // 32

// wave-synchronous LDS fence (wave-private LDS slices): no vmcnt drain
__device__ __forceinline__ void wave_sync_lds() {
  __builtin_amdgcn_sched_barrier(0);
  asm volatile("s_waitcnt lgkmcnt(0)" ::: "memory");
  __builtin_amdgcn_sched_barrier(0);
}

// ---------------- kernel 0: split Er f32 -> hi/lo bf16 ----------------
__global__ __launch_bounds__(256) void split_er_k(const float* __restrict__ er,
                                                  bf16* __restrict__ hi,
                                                  bf16* __restrict__ lo, int n) {
  int i = blockIdx.x * 256 + threadIdx.x;
  if (i < n) {
    float v = er[i];
    bf16 h = (bf16)v;
    hi[i] = h;
    lo[i] = (bf16)(v - (float)h);
  }
}

// ---------------- kernel 0b: transpose + split W [K][N] f32 -> WT [N][K] bf16 ----------------
__global__ __launch_bounds__(256) void trans_split_k(const float* __restrict__ W, int N, int K,
                                                     int n_lo, bf16* __restrict__ WT_h,
                                                     bf16* __restrict__ WT_l) {
  __shared__ float tile[64][68];
  const int n0 = blockIdx.x * 64, k0 = blockIdx.y * 64;
  const int t = threadIdx.x;
  const int rc = t & 15;
  const int rr0 = t >> 4;
#pragma unroll
  for (int i = 0; i < 4; ++i) {
    const int row = rr0 + i * 16;
    float4 v = *(const float4*)(W + (size_t)(k0 + row) * N + n0 + rc * 4);
    *(float4*)&tile[row][rc * 4] = v;
  }
  __syncthreads();
  const int n = t >> 2, kc = (t & 3) * 16;
  bf16x8 h0, h1, l0, l1;
#pragma unroll
  for (int e = 0; e < 8; ++e) {
    float v = tile[kc + e][n];
    bf16 hh = (bf16)v;
    h0[e] = hh;
    l0[e] = (bf16)(v - (float)hh);
  }
#pragma unroll
  for (int e = 0; e < 8; ++e) {
    float v = tile[kc + 8 + e][n];
    bf16 hh = (bf16)v;
    h1[e] = hh;
    l1[e] = (bf16)(v - (float)hh);
  }
  bf16* dst = WT_h + (size_t)(n0 + n) * K + k0 + kc;
  *(bf16x8*)dst = h0;
  *(bf16x8*)(dst + 8) = h1;
  if (WT_l != nullptr && (n0 + n) < n_lo) {
    bf16* dstl = WT_l + (size_t)(n0 + n) * K + k0 + kc;
    *(bf16x8*)dstl = l0;
    *(bf16x8*)(dstl + 8) = l1;
  }
}

// ---------------- kernel 1: QKV projection GEMM ----------------
__global__ __launch_bounds__(256) void qkv_gemm_k(const float* __restrict__ X,
                                                  const bf16* __restrict__ WTh,
                                                  const bf16* __restrict__ WTl,
                                                  const float* __restrict__ bias,
                                                  bf16* __restrict__ qh, bf16* __restrict__ ql,
                                                  bf16* __restrict__ kk, bf16* __restrict__ vt) {
  __shared__ bf16 xh[64][40], xl[64][40], wh[64][40], wl[64][40];
  const int t = threadIdx.x;
  const int lane = t & 63;
  const int wm = t >> 6;
  const int cl = lane & 15;
  const int g = lane >> 4;
  const int n0 = blockIdx.x * 64;
  const int m0 = blockIdx.y * 64;
  const bool isQ = (n0 < ND);

  f32x4 acc[4] = {};
  const int xrow = t >> 2, xkc = (t & 3) * 8;

  for (int k0 = 0; k0 < ND; k0 += 32) {
    {
      const float* xp = X + (size_t)(m0 + xrow) * ND + k0 + xkc;
      float4 v0 = *(const float4*)xp;
      float4 v1 = *(const float4*)(xp + 4);
      float v[8] = {v0.x, v0.y, v0.z, v0.w, v1.x, v1.y, v1.z, v1.w};
      bf16x8 h8, l8;
#pragma unroll
      for (int e = 0; e < 8; ++e) {
        bf16 hh = (bf16)v[e];
        h8[e] = hh;
        l8[e] = (bf16)(v[e] - (float)hh);
      }
      *(bf16x8*)&xh[xrow][xkc] = h8;
      if (isQ) *(bf16x8*)&xl[xrow][xkc] = l8;
    }
    {
      *(bf16x8*)&wh[xrow][xkc] = *(const bf16x8*)(WTh + (size_t)(n0 + xrow) * ND + k0 + xkc);
      if (isQ) *(bf16x8*)&wl[xrow][xkc] = *(const bf16x8*)(WTl + (size_t)(n0 + xrow) * ND + k0 + xkc);
    }
    __syncthreads();
    bf16x8 ah = *(const bf16x8*)&xh[wm * 16 + cl][g * 8];
    bf16x8 al = {};
    if (isQ) al = *(const bf16x8*)&xl[wm * 16 + cl][g * 8];
#pragma unroll
    for (int nf = 0; nf < 4; ++nf) {
      bf16x8 bh8 = *(const bf16x8*)&wh[nf * 16 + cl][g * 8];
      acc[nf] = MFMA16x16x32(ah, bh8, acc[nf]);
      if (isQ) {
        bf16x8 bl8 = *(const bf16x8*)&wl[nf * 16 + cl][g * 8];
        acc[nf] = MFMA16x16x32(ah, bl8, acc[nf]);
        acc[nf] = MFMA16x16x32(al, bh8, acc[nf]);
      }
    }
    __syncthreads();
  }

#pragma unroll
  for (int nf = 0; nf < 4; ++nf) {
#pragma unroll
    for (int reg = 0; reg < 4; ++reg) {
      const int gm = m0 + wm * 16 + g * 4 + reg;
      const int gn = n0 + nf * 16 + cl;
      float val = acc[nf][reg] + bias[gn];
      const int bb = gm >> 10, lpos = gm & 1023;
      const int sec = gn >> 10, hc = gn & 1023;
      const int hh = hc >> 6, dd = hc & 63;
      const int bh = bb * NH + hh;
      if (sec == 0) {
        bf16 hi = (bf16)val;
        qh[(size_t)(bh * NL + lpos) * NHD + dd] = hi;
        ql[(size_t)(bh * NL + lpos) * NHD + dd] = (bf16)(val - (float)hi);
      } else if (sec == 1) {
        kk[(size_t)(bh * NL + lpos) * NHD + dd] = (bf16)val;
      } else {
        vt[(size_t)(bh * NHD + dd) * NL + lpos] = (bf16)val;
      }
    }
  }
}

// ---------------- kernel 2: attention, v4 ----------------
// R2-proven per-chunk math + (a) XCD-chunked block mapping, (b) 4 waves/block
// splitting j-chunks mod 4 with flash-merge. LDS slices are wave-private.
__global__ __launch_bounds__(256) void attn_k(const bf16* __restrict__ qh, const bf16* __restrict__ ql,
                                              const bf16* __restrict__ kk, const bf16* __restrict__ vt,
                                              const bf16* __restrict__ erh, const bf16* __restrict__ erl,
                                              bf16* __restrict__ ao) {
  __shared__ float s_lds[4][16][68];  // S spill; reused as obuf in the merge epilogue
  __shared__ float e_lds[4][16][84];
  __shared__ bf16 p_lds[4][16][72];
  __shared__ float mb[4][16], lbuf[4][16], linv[16];

  const int t = threadIdx.x;
  const int w = t >> 6;
  const int lane = t & 63;
  const int cl = lane & 15;
  const int g = lane >> 4;

  // XCD-chunked mapping: each XCD gets 4 consecutive bh (Er/K/V ~4MB, L2-resident)
  const int n = blockIdx.x;
  const int xcd = n & 7, idx = n >> 3;
  const int bh = (xcd << 2) | (idx >> 6);
  const int itile = 63 - (idx & 63);  // long blocks dispatch first
  const int i0 = itile * 16;
  const int h = bh & (NH - 1);
  const int nchunks = (itile >> 2) + 1;

  // Q fragments (A-frag: row = lane&15, k = g*8+e)
  const bf16* qhb = qh + (size_t)(bh * NL + i0 + cl) * NHD + g * 8;
  const bf16* qlb = ql + (size_t)(bh * NL + i0 + cl) * NHD + g * 8;
  const bf16x8 q_h0 = *(const bf16x8*)qhb;
  const bf16x8 q_h1 = *(const bf16x8*)(qhb + 32);
  const bf16x8 q_l0 = *(const bf16x8*)qlb;
  const bf16x8 q_l1 = *(const bf16x8*)(qlb + 32);

  f32x4 acc_o[4] = {};
  float m_s = -3e38f, l_s = 0.0f;

  for (int jc = w; jc < nchunks; jc += 4) {
    const int j0 = jc * 64;
    const int delta = i0 - j0;  // >= 0, multiple of 16

    // ---- V fragments first (independent; hides latency) ----
    bf16x8 vf[4][2];
#pragma unroll
    for (int t4 = 0; t4 < 4; ++t4) {
      const bf16* vb = vt + (size_t)(bh * NHD + t4 * 16 + cl) * NL + j0 + g * 8;
      vf[t4][0] = *(const bf16x8*)vb;
      vf[t4][1] = *(const bf16x8*)(vb + 32);
    }

    // ---- S = Q K^T (hi only): D[q_sub=g*4+reg][j_sub=cl] per jn tile ----
    f32x4 acc_s[4];
#pragma unroll
    for (int jn = 0; jn < 4; ++jn) {
      const bf16* kb = kk + (size_t)(bh * NL + j0 + jn * 16 + cl) * NHD + g * 8;
      bf16x8 kf0 = *(const bf16x8*)kb;
      bf16x8 kf1 = *(const bf16x8*)(kb + 32);
      f32x4 a = {};
      a = MFMA16x16x32(q_h0, kf0, a);
      a = MFMA16x16x32(q_h1, kf1, a);
      acc_s[jn] = a;
    }

    // ---- bias: 5 Er tiles, o = i-j in [delta-64, delta+15], 3-term split ----
    f32x4 acc_e[5];
#pragma unroll
    for (int tt = 0; tt < 5; ++tt) {
      const int o = delta - 64 + tt * 16 + cl;
      const int p = (o <= 0) ? -o : (NP - o);  // (j-i) mod P
      const bf16* ebh = erh + (size_t)(h * NP + p) * NHD + g * 8;
      const bf16* ebl = erl + (size_t)(h * NP + p) * NHD + g * 8;
      bf16x8 eh0 = *(const bf16x8*)ebh;
      bf16x8 eh1 = *(const bf16x8*)(ebh + 32);
      bf16x8 el0 = *(const bf16x8*)ebl;
      bf16x8 el1 = *(const bf16x8*)(ebl + 32);
      f32x4 c1 = {}, c2 = {};
      c1 = MFMA16x16x32(q_h0, eh0, c1);
      c1 = MFMA16x16x32(q_h1, eh1, c1);
      c2 = MFMA16x16x32(q_h0, el0, c2);
      c2 = MFMA16x16x32(q_h1, el1, c2);
      c2 = MFMA16x16x32(q_l0, eh0, c2);
      c2 = MFMA16x16x32(q_l1, eh1, c2);
      acc_e[tt] = c1 + c2;
    }

    // ---- spill S and E to wave-private LDS ----
#pragma unroll
    for (int reg = 0; reg < 4; ++reg) {
      const int row = g * 4 + reg;
#pragma unroll
      for (int jn = 0; jn < 4; ++jn) s_lds[w][row][jn * 16 + cl] = acc_s[jn][reg];
#pragma unroll
      for (int tt = 0; tt < 5; ++tt) e_lds[w][row][tt * 16 + cl] = acc_e[tt][reg];
    }
    wave_sync_lds();

    // ---- online softmax; lane handles row=cl, cols g*16..g*16+15 ----
    float sv[16];
    float tmax = -3e38f;
#pragma unroll
    for (int cc = 0; cc < 16; ++cc) {
      const int c = g * 16 + cc;
      float v = fmaf(s_lds[w][cl][c], 0.125f, e_lds[w][cl][cl - c + 64]);  // idx in [1,79]
      if (c > delta + cl) v = -3e38f;  // causal mask
      sv[cc] = v;
      tmax = fmaxf(tmax, v);
    }
    tmax = fmaxf(tmax, __shfl_xor(tmax, 16));
    tmax = fmaxf(tmax, __shfl_xor(tmax, 32));
    const float m_new = fmaxf(m_s, tmax);
    const float fsc = __builtin_amdgcn_exp2f((m_s - m_new) * 1.44269504f);
    float psum = 0.0f;
    bf16x8 plo, phi;
#pragma unroll
    for (int cc = 0; cc < 16; ++cc) {
      float pv = __builtin_amdgcn_exp2f((sv[cc] - m_new) * 1.44269504f);
      psum += pv;
      if (cc < 8) plo[cc & 7] = (bf16)pv;
      else        phi[cc & 7] = (bf16)pv;
    }
    psum += __shfl_xor(psum, 16);
    psum += __shfl_xor(psum, 32);
    l_s = l_s * fsc + psum;
    m_s = m_new;

    // P -> LDS (row=cl, cols g*16..+15), read back in A-frag layout
    *(bf16x8*)&p_lds[w][cl][g * 16] = plo;
    *(bf16x8*)&p_lds[w][cl][g * 16 + 8] = phi;
    wave_sync_lds();
    bf16x8 pf0 = *(const bf16x8*)&p_lds[w][cl][g * 8];
    bf16x8 pf1 = *(const bf16x8*)&p_lds[w][cl][32 + g * 8];

    // rescale O per row (factors via shfl), accumulate PV
    float fr[4];
#pragma unroll
    for (int reg = 0; reg < 4; ++reg) fr[reg] = __shfl(fsc, g * 4 + reg);
#pragma unroll
    for (int t4 = 0; t4 < 4; ++t4) {
#pragma unroll
      for (int reg = 0; reg < 4; ++reg) acc_o[t4][reg] *= fr[reg];
    }
#pragma unroll
    for (int t4 = 0; t4 < 4; ++t4) {
      acc_o[t4] = MFMA16x16x32(pf0, vf[t4][0], acc_o[t4]);
      acc_o[t4] = MFMA16x16x32(pf1, vf[t4][1], acc_o[t4]);
    }
  }

  // ---- flash-merge the 4 waves' partials (s_lds reused as obuf) ----
  if (lane < 16) {
    mb[w][lane] = m_s;
    lbuf[w][lane] = l_s;
  }
  __syncthreads();
  const float M = fmaxf(fmaxf(mb[0][cl], mb[1][cl]), fmaxf(mb[2][cl], mb[3][cl]));
  const float sc = __builtin_amdgcn_exp2f((m_s - M) * 1.44269504f);
  float Lt = 0.0f;
#pragma unroll
  for (int ww = 0; ww < 4; ++ww)
    Lt += lbuf[ww][cl] * __builtin_amdgcn_exp2f((mb[ww][cl] - M) * 1.44269504f);
  if (w == 0 && lane < 16) linv[lane] = 1.0f / Lt;
  float fr2[4];
#pragma unroll
  for (int reg = 0; reg < 4; ++reg) fr2[reg] = __shfl(sc, g * 4 + reg);
#pragma unroll
  for (int t4 = 0; t4 < 4; ++t4) {
#pragma unroll
    for (int reg = 0; reg < 4; ++reg)
      s_lds[w][g * 4 + reg][t4 * 16 + cl] = acc_o[t4][reg] * fr2[reg];
  }
  __syncthreads();
  const int bb = bh >> 4;  // NH == 16
#pragma unroll
  for (int rep = 0; rep < 4; ++rep) {
    const int o_ = t + rep * 256;
    const int r = o_ >> 6, c = o_ & 63;
    float s = s_lds[0][r][c] + s_lds[1][r][c] + s_lds[2][r][c] + s_lds[3][r][c];
    ao[(size_t)(bb * NL + i0 + r) * ND + h * NHD + c] = (bf16)(s * linv[r]);
  }
}

// ---------------- kernel 3: output projection ----------------
__global__ __launch_bounds__(256) void out_gemm_k(const bf16* __restrict__ A,
                                                  const bf16* __restrict__ WT,
                                                  const float* __restrict__ bias,
                                                  float* __restrict__ out) {
  __shared__ bf16 alds[64][40], wh[64][40];
  const int t = threadIdx.x;
  const int lane = t & 63, wm = t >> 6;
  const int cl = lane & 15, g = lane >> 4;
  const int n0 = blockIdx.x * 64, m0 = blockIdx.y * 64;
  f32x4 acc[4] = {};
  const int arow = t >> 2, akc = (t & 3) * 8;
  for (int k0 = 0; k0 < ND; k0 += 32) {
    *(bf16x8*)&alds[arow][akc] = *(const bf16x8*)(A + (size_t)(m0 + arow) * ND + k0 + akc);
    *(bf16x8*)&wh[arow][akc] = *(const bf16x8*)(WT + (size_t)(n0 + arow) * ND + k0 + akc);
    __syncthreads();
    bf16x8 a8 = *(const bf16x8*)&alds[wm * 16 + cl][g * 8];
#pragma unroll
    for (int nf = 0; nf < 4; ++nf) {
      bf16x8 b8 = *(const bf16x8*)&wh[nf * 16 + cl][g * 8];
      acc[nf] = MFMA16x16x32(a8, b8, acc[nf]);
    }
    __syncthreads();
  }
#pragma unroll
  for (int nf = 0; nf < 4; ++nf) {
#pragma unroll
    for (int reg = 0; reg < 4; ++reg) {
      const int gm = m0 + wm * 16 + g * 4 + reg;
      const int gn = n0 + nf * 16 + cl;
      out[(size_t)gm * ND + gn] = acc[nf][reg] + bias[gn];
    }
  }
}

extern "C" void kernel_launch(void* const* d_in, const int* in_sizes, int n_in,
                              void* d_out, int out_size, void* d_ws, size_t ws_size,
                              hipStream_t stream) {
  (void)in_sizes; (void)n_in; (void)out_size; (void)ws_size;
  const float* x = (const float*)d_in[0];
  // d_in[1] = causal mask — structural (triu k=1), computed inline
  const float* Wqkv = (const float*)d_in[2];
  const float* bqkv = (const float*)d_in[3];
  const float* Wo = (const float*)d_in[4];
  const float* bo = (const float*)d_in[5];
  const float* Er = (const float*)d_in[6];

  char* ws = (char*)d_ws;
  size_t off = 0;
  auto take = [&](size_t bytes) {
    char* p = ws + off;
    off += (bytes + 255) & ~(size_t)255;
    return p;
  };
  const size_t erN = (size_t)NH * NP * NHD;   // 2,096,128
  const size_t qkN = (size_t)NBH * NL * NHD;  // 2,097,152
  bf16* erh = (bf16*)take(erN * 2);
  bf16* erl = (bf16*)take(erN * 2);
  bf16* qhw = (bf16*)take(qkN * 2);
  bf16* qlw = (bf16*)take(qkN * 2);
  bf16* kw  = (bf16*)take(qkN * 2);
  bf16* vtw = (bf16*)take(qkN * 2);
  bf16* wqkvth = (bf16*)take((size_t)3 * ND * ND * 2);  // [3072][1024]
  bf16* wqkvtl = (bf16*)take((size_t)ND * ND * 2);      // [1024][1024] (Q section only)
  bf16* woth   = (bf16*)take((size_t)ND * ND * 2);      // [1024][1024]
  bf16* aow = wqkvth;  // alias: wqkvth dead after qkv_gemm, aow born in attn

  split_er_k<<<(int)((erN + 255) / 256), 256, 0, stream>>>(Er, erh, erl, (int)erN);
  trans_split_k<<<dim3(48, 16), 256, 0, stream>>>(Wqkv, 3 * ND, ND, ND, wqkvth, wqkvtl);
  trans_split_k<<<dim3(16, 16), 256, 0, stream>>>(Wo, ND, ND, 0, woth, nullptr);
  qkv_gemm_k<<<dim3(48, 32), 256, 0, stream>>>(x, wqkvth, wqkvtl, bqkv, qhw, qlw, kw, vtw);
  attn_k<<<2048, 256, 0, stream>>>(qhw, qlw, kw, vtw, erh, erl, aow);
  out_gemm_k<<<dim3(16, 32), 256, 0, stream>>>(aow, woth, bo, (float*)d_out);
}